// Round 1
// baseline (302.293 us; speedup 1.0000x reference)
//
#include <hip/hip_runtime.h>

#define T_SEQ 128
#define NF 256
#define NH 30
#define NG 120           // 4*NH
#define NBATCH 1024
#define M_ROWS (NBATCH * T_SEQ)   // 131072

// ws byte offsets:
//   [0, 512)          bias0c[128] = permuted(b_ih0 + b_hh0), zero-padded to 128
//   [1024, 66560)     Bfrag_hi: [8 ktiles][8 subtiles][64 lanes][8 bf16]  (64 KB)
//   [66560, 132096)   Bfrag_lo: same shape (64 KB)
//   [132096, ...)     xg: [M_ROWS][120] fp32, COLUMN-PERMUTED: col' = 4*j + gate
#define BIAS_OFF 0
#define BHI_OFF  1024
#define BLO_OFF  (BHI_OFF + 65536)
#define XG_OFF_B (BLO_OFF + 65536)   // 132096 bytes = 33024 floats

typedef __attribute__((ext_vector_type(8))) short short8;
typedef __attribute__((ext_vector_type(2))) float float2v;
typedef __attribute__((ext_vector_type(4))) float float4v;

// ---------------------------------------------------------------- helpers
__device__ __forceinline__ short bf16_of(float f) {
  union { float f; unsigned u; } v; v.f = f;
  unsigned r = v.u + 0x7fffu + ((v.u >> 16) & 1u);  // RNE
  return (short)(r >> 16);
}
__device__ __forceinline__ float f_of_bf16(short s) {
  union { unsigned u; float f; } v; v.u = ((unsigned)(unsigned short)s) << 16;
  return v.f;
}

__device__ __forceinline__ float fast_rcp(float x) { return __builtin_amdgcn_rcpf(x); }

// exp2-based activations (fold log2(e) into the gate scale: saves the hidden
// mul inside __expf). sigmoid(x) = 1/(1+2^(-L2E x)); tanh via 2*sigm(2x)-1.
#define L2E 1.4426950408889634f
__device__ __forceinline__ float sigm_fast(float x) {
  float e = __builtin_amdgcn_exp2f(-L2E * x);
  return fast_rcp(1.0f + e);
}
__device__ __forceinline__ float act_a(float x, float kIn_l2, float kOut, float cOut) {
  float e = __builtin_amdgcn_exp2f(-kIn_l2 * x);
  return fmaf(kOut, fast_rcp(1.0f + e), cOut);
}
__device__ __forceinline__ float tanh_fast(float x) {
  float e = __builtin_amdgcn_exp2f(-2.0f * L2E * x);
  return fmaf(2.0f, fast_rcp(1.0f + e), -1.0f);
}

__device__ __forceinline__ float2v fma2(float2v a, float2v b, float2v c) {
  return __builtin_elementwise_fma(a, b, c);   // -> v_pk_fma_f32
}

// ---------------------------------------------------------------- prep
// Splits w_ih0 into bf16 hi/lo planes in MFMA B-fragment order, with the
// OUTPUT COLUMNS PERMUTED: new col n holds original gate row
// orig(n) = (n&3)*30 + (n>>2), i.e. col' = 4*j + gate. This makes the lstm
// kernel's two gate inputs per lane adjacent (one dwordx2 load).
__global__ void prep_kernel(const float* __restrict__ w_ih0,
                            const float* __restrict__ b_ih0,
                            const float* __restrict__ b_hh0,
                            unsigned char* __restrict__ ws) {
  int gid = blockIdx.x * 256 + threadIdx.x;   // 0..4095 = (t*8+s)*64 + lane
  float* bias = (float*)(ws + BIAS_OFF);
  if (gid < 128) {
    int og = (gid & 3) * NH + (gid >> 2);
    bias[gid] = (gid < NG) ? (b_ih0[og] + b_hh0[og]) : 0.0f;
  }

  int lane = gid & 63;
  int ts = gid >> 6;
  int t = ts >> 3, s = ts & 7;
  int n = s * 16 + (lane & 15);               // new (permuted) column
  int orig = (n & 3) * NH + (n >> 2);         // original gate row of w_ih0
  int k0 = t * 32 + (lane >> 4) * 8;

  short8 hi, lo;
#pragma unroll
  for (int j = 0; j < 8; ++j) {
    float v = (n < NG) ? w_ih0[orig * NF + k0 + j] : 0.0f;
    short h = bf16_of(v);
    hi[j] = h;
    lo[j] = bf16_of(v - f_of_bf16(h));
  }
  *(short8*)(ws + BHI_OFF + (size_t)gid * 16) = hi;
  *(short8*)(ws + BLO_OFF + (size_t)gid * 16) = lo;
}

// ---------------------------------------------------------------- GEMM: xg = x @ w_ih0^T + bias (split-bf16 MFMA)
// (unchanged — column permutation is entirely inside the prep packing)
__global__ __launch_bounds__(256, 3) void gemm_xg(const float* __restrict__ x,
                                                  const unsigned char* __restrict__ ws,
                                                  float* __restrict__ xg) {
  __shared__ short lds_B[2][8 * 2 * 64 * 8];   // [buf][(s*2+plane)*64 + lane][8]
  const int tid = threadIdx.x;
  const int lane = tid & 63;
  const int wave = tid >> 6;
  const int r15 = lane & 15;
  const int quad = lane >> 4;
  const int rowbase = blockIdx.x * 128 + wave * 32;

  const short* __restrict__ Bhi = (const short*)(ws + BHI_OFF);
  const short* __restrict__ Blo = (const short*)(ws + BLO_OFF);
  const float* __restrict__ bias = (const float*)(ws + BIAS_OFF);

  float4v acc[2][8];
#pragma unroll
  for (int s = 0; s < 8; ++s) {
    float b = bias[s * 16 + r15];
    float4v bv = {b, b, b, b};
    acc[0][s] = bv;
    acc[1][s] = bv;
  }

  const float* xptr[2];
  xptr[0] = x + (size_t)(rowbase + r15) * NF + quad * 8;
  xptr[1] = x + (size_t)(rowbase + 16 + r15) * NF + quad * 8;

#pragma unroll
  for (int i = 0; i < 2; ++i) {
    int s = wave * 2 + i;
    const short* ghi = Bhi + ((size_t)(0 * 8 + s) * 64 + lane) * 8;
    const short* glo = Blo + ((size_t)(0 * 8 + s) * 64 + lane) * 8;
    short* lhi = &lds_B[0][(s * 2 + 0) * 64 * 8];
    short* llo = &lds_B[0][(s * 2 + 1) * 64 * 8];
    __builtin_amdgcn_global_load_lds((const __attribute__((address_space(1))) void*)ghi,
                                     (__attribute__((address_space(3))) void*)lhi, 16, 0, 0);
    __builtin_amdgcn_global_load_lds((const __attribute__((address_space(1))) void*)glo,
                                     (__attribute__((address_space(3))) void*)llo, 16, 0, 0);
  }

  short8 ahi[2], alo[2];
#pragma unroll
  for (int g = 0; g < 2; ++g) {
    float4 p0 = *(const float4*)(xptr[g] + 0);
    float4 p1 = *(const float4*)(xptr[g] + 4);
    float f[8] = {p0.x, p0.y, p0.z, p0.w, p1.x, p1.y, p1.z, p1.w};
#pragma unroll
    for (int j = 0; j < 8; ++j) {
      short h = bf16_of(f[j]);
      ahi[g][j] = h;
      alo[g][j] = bf16_of(f[j] - f_of_bf16(h));
    }
  }
  __syncthreads();

  for (int t = 0; t < 8; ++t) {
    const int buf = t & 1;
    float4 anx[2][2];
    if (t < 7) {
#pragma unroll
      for (int i = 0; i < 2; ++i) {
        int s = wave * 2 + i;
        const short* ghi = Bhi + ((size_t)((t + 1) * 8 + s) * 64 + lane) * 8;
        const short* glo = Blo + ((size_t)((t + 1) * 8 + s) * 64 + lane) * 8;
        short* lhi = &lds_B[buf ^ 1][(s * 2 + 0) * 64 * 8];
        short* llo = &lds_B[buf ^ 1][(s * 2 + 1) * 64 * 8];
        __builtin_amdgcn_global_load_lds((const __attribute__((address_space(1))) void*)ghi,
                                         (__attribute__((address_space(3))) void*)lhi, 16, 0, 0);
        __builtin_amdgcn_global_load_lds((const __attribute__((address_space(1))) void*)glo,
                                         (__attribute__((address_space(3))) void*)llo, 16, 0, 0);
      }
#pragma unroll
      for (int g = 0; g < 2; ++g) {
        anx[g][0] = *(const float4*)(xptr[g] + (t + 1) * 32);
        anx[g][1] = *(const float4*)(xptr[g] + (t + 1) * 32 + 4);
      }
    }

#pragma unroll
    for (int s = 0; s < 8; ++s) {
      const short8 bh = *(const short8*)&lds_B[buf][((s * 2 + 0) * 64 + lane) * 8];
      const short8 bl = *(const short8*)&lds_B[buf][((s * 2 + 1) * 64 + lane) * 8];
#pragma unroll
      for (int g = 0; g < 2; ++g) {
        acc[g][s] = __builtin_amdgcn_mfma_f32_16x16x32_bf16(ahi[g], bh, acc[g][s], 0, 0, 0);
        acc[g][s] = __builtin_amdgcn_mfma_f32_16x16x32_bf16(ahi[g], bl, acc[g][s], 0, 0, 0);
        acc[g][s] = __builtin_amdgcn_mfma_f32_16x16x32_bf16(alo[g], bh, acc[g][s], 0, 0, 0);
      }
    }

    if (t < 7) {
#pragma unroll
      for (int g = 0; g < 2; ++g) {
        float f[8] = {anx[g][0].x, anx[g][0].y, anx[g][0].z, anx[g][0].w,
                      anx[g][1].x, anx[g][1].y, anx[g][1].z, anx[g][1].w};
#pragma unroll
        for (int j = 0; j < 8; ++j) {
          short h = bf16_of(f[j]);
          ahi[g][j] = h;
          alo[g][j] = bf16_of(f[j] - f_of_bf16(h));
        }
      }
    }
    __syncthreads();
  }

#pragma unroll
  for (int g = 0; g < 2; ++g) {
    const int row0 = rowbase + g * 16 + quad * 4;
#pragma unroll
    for (int s = 0; s < 8; ++s) {
      const int col = s * 16 + r15;
      if (col < NG) {
#pragma unroll
        for (int i = 0; i < 4; ++i) {
          xg[(size_t)(row0 + i) * NG + col] = acc[g][s][i];
        }
      }
    }
  }
}

// ---------------------------------------------------------------- fused 2-layer recurrence + linear
// One wave per batch element (1024 waves = 1/SIMD exactly — occupancy is
// batch-limited, so VGPRs are free: __launch_bounds__(64,1) unlocks the full
// register file and all 180 weight floats stay register-resident).
// h-broadcast: scatter h (30 lanes) to LDS once per layer-step, read back as
// uniform-address float4 loads (HW broadcast) -> {h_2p,h_2p+1} pairs feed
// packed v_pk_fma_f32 dot products (2 gates x 15 pairs = 30 pk_fma/matvec,
// replacing 30 readlane + 60 scalar fma). The h0 LDS round-trip latency is
// covered by the layer-1 u-matvec (depends only on old h1).
__global__ __launch_bounds__(64, 1) void lstm_fused(const float* __restrict__ xg,
                                                    const float* __restrict__ w_hh0,
                                                    const float* __restrict__ w_ih1,
                                                    const float* __restrict__ w_hh1,
                                                    const float* __restrict__ b_ih1,
                                                    const float* __restrict__ b_hh1,
                                                    const float* __restrict__ w_lin,
                                                    const float* __restrict__ b_lin,
                                                    float* __restrict__ out) {
  __shared__ __align__(16) float hbuf0[32];
  __shared__ __align__(16) float hbuf1[32];
  const int b = blockIdx.x;
  const int lane = threadIdx.x;
  const bool hiHalf = lane >= 32;
  const int l = hiHalf ? (lane - 32) : lane;
  const int lc = (l < NH) ? l : (NH - 1);
  const int gA = hiHalf ? (60 + lc) : lc;     // lo: i-gate, hi: g-gate
  const int gB = gA + NH;                     // lo: f-gate, hi: o-gate

  const float kInA = (hiHalf ? 2.0f : 1.0f) * L2E;   // aA: sigmoid (lo) / tanh (hi)
  const float kOutA = hiHalf ? 2.0f : 1.0f;
  const float cOutA = hiHalf ? -1.0f : 0.0f;

  // per-lane weights for this lane's two gates, packed over j-pairs
  float2v W0A[15], W0B[15], V1A[15], V1B[15], U1A[15], U1B[15];
#pragma unroll
  for (int p = 0; p < 15; ++p) {
    W0A[p] = *(const float2v*)&w_hh0[gA * NH + 2 * p];
    W0B[p] = *(const float2v*)&w_hh0[gB * NH + 2 * p];
    V1A[p] = *(const float2v*)&w_ih1[gA * NH + 2 * p];
    V1B[p] = *(const float2v*)&w_ih1[gB * NH + 2 * p];
    U1A[p] = *(const float2v*)&w_hh1[gA * NH + 2 * p];
    U1B[p] = *(const float2v*)&w_hh1[gB * NH + 2 * p];
  }
  const float bA1 = b_ih1[gA] + b_hh1[gA];
  const float bB1 = b_ih1[gB] + b_hh1[gB];

  // broadcast h state, register-resident as quads {h4k..h4k+3}
  float4v h0q[8], h1q[8];
#pragma unroll
  for (int k = 0; k < 8; ++k) {
    h0q[k] = float4v{0.f, 0.f, 0.f, 0.f};
    h1q[k] = float4v{0.f, 0.f, 0.f, 0.f};
  }

  float c0 = 0.0f, c1 = 0.0f, acc = 0.0f;
  const float* __restrict__ xgb = xg + (size_t)b * T_SEQ * NG;
  const int xoff = 4 * lc + (hiHalf ? 2 : 0);   // permuted xg: gates adjacent

  float2v xab[4];
  float wlr[4];
#pragma unroll
  for (int p = 0; p < 3; ++p) {
    xab[p] = *(const float2v*)&xgb[p * NG + xoff];
    wlr[p] = w_lin[p * NH + lc];
  }

#pragma unroll 4
  for (int t = 0; t < T_SEQ; ++t) {
    const int cur = t & 3;
    const int nxt = (t + 3) & 3;
    const int tp = (t + 3 < T_SEQ) ? (t + 3) : (T_SEQ - 1);
    float2v pxg = *(const float2v*)&xgb[tp * NG + xoff];
    float pwl = w_lin[tp * NH + lc];

    // ---- layer 0: gates = xg_t + h0_old @ W_hh0^T
    float2v a0A = {xab[cur].x, 0.f};
    float2v a0B = {xab[cur].y, 0.f};
#pragma unroll
    for (int k = 0; k < 8; ++k) {
      float2v hlo = __builtin_shufflevector(h0q[k], h0q[k], 0, 1);
      a0A = fma2(hlo, W0A[2 * k], a0A);
      a0B = fma2(hlo, W0B[2 * k], a0B);
      if (k < 7) {
        float2v hhi = __builtin_shufflevector(h0q[k], h0q[k], 2, 3);
        a0A = fma2(hhi, W0A[2 * k + 1], a0A);
        a0B = fma2(hhi, W0B[2 * k + 1], a0B);
      }
    }
    float sA = a0A.x + a0A.y;
    float sB = a0B.x + a0B.y;
    float aA = act_a(sA, kInA, kOutA, cOutA);
    float aB = sigm_fast(sB);
    float gg = __shfl_down(aA, 32);
    float oo = __shfl_down(aB, 32);
    c0 = fmaf(aB, c0, aA * gg);              // c = f*c + i*g   (lo lanes)
    float h0 = oo * tanh_fast(c0);           // h = o*tanh(c)
    if (lane < NH) hbuf0[lane] = h0;
#pragma unroll
    for (int k = 0; k < 8; ++k) h0q[k] = *(const float4v*)&hbuf0[4 * k];

    // ---- layer 1 u-part (old h1) — independent, hides h0 LDS round-trip
    float2v aUA = {bA1, 0.f};
    float2v aUB = {bB1, 0.f};
#pragma unroll
    for (int k = 0; k < 8; ++k) {
      float2v hlo = __builtin_shufflevector(h1q[k], h1q[k], 0, 1);
      aUA = fma2(hlo, U1A[2 * k], aUA);
      aUB = fma2(hlo, U1B[2 * k], aUB);
      if (k < 7) {
        float2v hhi = __builtin_shufflevector(h1q[k], h1q[k], 2, 3);
        aUA = fma2(hhi, U1A[2 * k + 1], aUA);
        aUB = fma2(hhi, U1B[2 * k + 1], aUB);
      }
    }

    // ---- layer 1 v-part (new h0)
    float2v aVA = {0.f, 0.f};
    float2v aVB = {0.f, 0.f};
#pragma unroll
    for (int k = 0; k < 8; ++k) {
      float2v hlo = __builtin_shufflevector(h0q[k], h0q[k], 0, 1);
      aVA = fma2(hlo, V1A[2 * k], aVA);
      aVB = fma2(hlo, V1B[2 * k], aVB);
      if (k < 7) {
        float2v hhi = __builtin_shufflevector(h0q[k], h0q[k], 2, 3);
        aVA = fma2(hhi, V1A[2 * k + 1], aVA);
        aVB = fma2(hhi, V1B[2 * k + 1], aVB);
      }
    }
    float s1A = (aUA.x + aUA.y) + (aVA.x + aVA.y);
    float s1B = (aUB.x + aUB.y) + (aVB.x + aVB.y);
    float a1A = act_a(s1A, kInA, kOutA, cOutA);
    float a1B = sigm_fast(s1B);
    float gg1 = __shfl_down(a1A, 32);
    float oo1 = __shfl_down(a1B, 32);
    c1 = fmaf(a1B, c1, a1A * gg1);
    float h1 = oo1 * tanh_fast(c1);
    if (lane < NH) hbuf1[lane] = h1;
#pragma unroll
    for (int k = 0; k < 8; ++k) h1q[k] = *(const float4v*)&hbuf1[4 * k];

    acc = fmaf(h1, wlr[cur], acc);

    xab[nxt] = pxg;
    wlr[nxt] = pwl;
  }

  if (lane >= NH) acc = 0.0f;
#pragma unroll
  for (int off = 32; off > 0; off >>= 1) acc += __shfl_xor(acc, off);
  if (lane == 0) out[b] = acc + b_lin[0];
}

// ---------------------------------------------------------------- launch
extern "C" void kernel_launch(void* const* d_in, const int* in_sizes, int n_in,
                              void* d_out, int out_size, void* d_ws, size_t ws_size,
                              hipStream_t stream) {
  (void)in_sizes; (void)n_in; (void)out_size; (void)ws_size;
  const float* x     = (const float*)d_in[0];
  const float* w_ih0 = (const float*)d_in[1];
  const float* w_hh0 = (const float*)d_in[2];
  const float* b_ih0 = (const float*)d_in[3];
  const float* b_hh0 = (const float*)d_in[4];
  const float* w_ih1 = (const float*)d_in[5];
  const float* w_hh1 = (const float*)d_in[6];
  const float* b_ih1 = (const float*)d_in[7];
  const float* b_hh1 = (const float*)d_in[8];
  const float* w_lin = (const float*)d_in[9];
  const float* b_lin = (const float*)d_in[10];
  unsigned char* ws = (unsigned char*)d_ws;
  float* out = (float*)d_out;
  float* xg = (float*)(ws + XG_OFF_B);

  prep_kernel<<<16, 256, 0, stream>>>(w_ih0, b_ih0, b_hh0, ws);
  gemm_xg<<<M_ROWS / 128, 256, 0, stream>>>(x, ws, xg);
  lstm_fused<<<NBATCH, 64, 0, stream>>>(xg, w_hh0, w_ih1, w_hh1,
                                        b_ih1, b_hh1, w_lin, b_lin, out);
}